// Round 9
// baseline (1366.540 us; speedup 1.0000x reference)
//
#include <hip/hip_runtime.h>

#define HDIM 64
#define EPSBN 1e-5f
#define MNODES 8

typedef unsigned short u16;

__device__ __forceinline__ float bf2f(u16 b) {
    return __uint_as_float(((unsigned)b) << 16);
}
__device__ __forceinline__ u16 f2bf_rne(float f) {
    unsigned u = __float_as_uint(f);
    u += 0x7FFFu + ((u >> 16) & 1u);      // round-to-nearest-even
    return (u16)(u >> 16);
}

// ---------------- degree count ----------------
__global__ void count_edges_k(const int* __restrict__ col, int* __restrict__ cnt, int E) {
    int e = blockIdx.x * blockDim.x + threadIdx.x;
    if (e < E) atomicAdd(&cnt[col[e]], 1);
}

// ---------------- exclusive scan of cnt -> offs ----------------
__global__ void scan_partial_k(const int* __restrict__ cnt, int* __restrict__ offs,
                               int* __restrict__ bsum, int n) {
    __shared__ int lds[256];
    int tid = threadIdx.x;
    int base = blockIdx.x * 1024 + tid * 4;
    int v0 = (base + 0 < n) ? cnt[base + 0] : 0;
    int v1 = (base + 1 < n) ? cnt[base + 1] : 0;
    int v2 = (base + 2 < n) ? cnt[base + 2] : 0;
    int v3 = (base + 3 < n) ? cnt[base + 3] : 0;
    int tsum = v0 + v1 + v2 + v3;
    lds[tid] = tsum;
    __syncthreads();
    for (int off = 1; off < 256; off <<= 1) {
        int t = (tid >= off) ? lds[tid - off] : 0;
        __syncthreads();
        lds[tid] += t;
        __syncthreads();
    }
    int excl = lds[tid] - tsum;
    if (tid == 255) bsum[blockIdx.x] = lds[255];
    int run = excl;
    if (base + 0 < n) { offs[base + 0] = run; } run += v0;
    if (base + 1 < n) { offs[base + 1] = run; } run += v1;
    if (base + 2 < n) { offs[base + 2] = run; } run += v2;
    if (base + 3 < n) { offs[base + 3] = run; }
}

// adds block bases (re-scans <=256 block sums in-block), writes cursor + dinv
__global__ void scan_add_k(const int* __restrict__ cnt, int* __restrict__ offs,
                           const int* __restrict__ bsum, int nb,
                           int* __restrict__ cursor, float* __restrict__ dinv,
                           int n, int Etot) {
    __shared__ int lds[256];
    int tid = threadIdx.x;
    int v = (tid < nb) ? bsum[tid] : 0;
    lds[tid] = v;
    __syncthreads();
    for (int off = 1; off < 256; off <<= 1) {
        int t = (tid >= off) ? lds[tid - off] : 0;
        __syncthreads();
        lds[tid] += t;
        __syncthreads();
    }
    int excl = lds[tid] - v;
    __syncthreads();
    lds[tid] = excl;
    __syncthreads();

    int i = blockIdx.x * blockDim.x + tid;
    if (i < n) {
        int o = offs[i] + lds[i >> 10];
        offs[i] = o;
        cursor[i] = o;
        dinv[i] = rsqrtf((float)cnt[i] + 1.0f);   // +1 for self-loop
    }
    if (i == 0) offs[n] = Etot;
}

// ---------------- CSR fill with REAL XCD ownership + work stealing ----------------
// Each block reads its actual XCC via s_getreg(HW_REG_XCC_ID=20, offset 0, size 4).
// 8 owner-classes; blocks claim 256-edge chunks from per-class atomic counters,
// own class first then steal. Every (chunk, class) pair is processed exactly once
// for ANY xcc readings -> correctness is scheduler-independent; when xcc is real,
// node c's srcw lines are produced inside XCD owner(c)'s L2 -> full-line evictions.
// Also pads x [N][26] -> xp [N][32] via grid-stride.
__global__ __launch_bounds__(256) void fillpad_k(
    const int* __restrict__ row, const int* __restrict__ col,
    const float* __restrict__ dinv, int* __restrict__ cursor,
    int2* __restrict__ srcw, int E, int N,
    const float* __restrict__ x, float* __restrict__ xp, int INR, int padTot,
    int* __restrict__ ctr, int nchunks, int nblocks) {
    int tid = threadIdx.x;
    for (int p = blockIdx.x * 256 + tid; p < padTot; p += nblocks * 256) {
        int i = p >> 5, k = p & 31;
        xp[p] = (k < INR) ? x[i * INR + k] : 0.f;
    }
    int xcc = __builtin_amdgcn_s_getreg(6164) & 7;   // hwreg(XCC_ID=20, 0, 4)
    __shared__ int sC;
    for (int t = 0; t < 8; t++) {
        int q = (xcc + t) & 7;
        while (true) {
            __syncthreads();
            if (tid == 0) sC = atomicAdd(&ctr[q], 1);
            __syncthreads();
            int c = sC;
            if (c >= nchunks) break;
            int e = c * 256 + tid;
            if (e >= E) continue;
            int cc = col[e];
            int owner = (int)(((unsigned long long)cc * 8ull) / (unsigned)N);
            if (owner != q) continue;
            int r = row[e];
            float w = dinv[r] * dinv[cc];
            int pos = atomicAdd(&cursor[cc], 1);
            srcw[pos] = make_int2(r, __float_as_int(w));
        }
    }
}

// ---------------- fused conv: 2 waves split each node's edge list ----------------
// 128-thr block, MNODES nodes serial. Wave w gathers edges [half w) with the
// R7-proven 8/4/1 inner loop; partials meet in LDS (2-barrier pattern); wave 0
// does dense+BN+ReLU+store while wave 1 runs ahead into the next node's gather.
// INBF: features stored bf16 (128 B rows); all arithmetic f32.
template <int KIN, bool INBF, bool OUTBF>
__global__ __launch_bounds__(128) void conv_k(
    const void* __restrict__ hin_, const int* __restrict__ offs,
    const int2* __restrict__ srcw, const float* __restrict__ dinv,
    const float* __restrict__ W, int KINR,
    const float* __restrict__ bias, const float* __restrict__ g,
    const float* __restrict__ bb, const float* __restrict__ m,
    const float* __restrict__ v, void* __restrict__ hout_, int n) {
    const float* hf = (const float*)hin_;
    const u16*   hb = (const u16*)hin_;
    const int tid = threadIdx.x;
    const int wv = tid >> 6, lane = tid & 63;
    float wreg[KIN];
#pragma unroll
    for (int k = 0; k < KIN; k++) wreg[k] = (k < KINR) ? W[k * HDIM + lane] : 0.f;
    const float sc = g[lane] * rsqrtf(v[lane] + EPSBN);
    const float sh = (bias[lane] - m[lane]) * sc + bb[lane];

    __shared__ float aggP[2][HDIM];

    auto ldh = [&](int node) -> float {
        if (INBF) return bf2f(hb[(size_t)node * KIN + lane]);
        return (lane < KIN) ? hf[(size_t)node * KIN + lane] : 0.f;
    };

    int i0 = blockIdx.x * MNODES;
    for (int j = 0; j < MNODES; j++) {
        int i = i0 + j;
        if (i >= n) break;                  // block-uniform
        float di = dinv[i];
        int e0 = offs[i], s1 = offs[i + 1];
        int mid = e0 + ((s1 - e0 + 1) >> 1);
        int e = wv ? mid : e0;
        int eend = wv ? s1 : mid;
        float acc = (wv == 0) ? ldh(i) * (di * di) : 0.f;   // self-loop in wave 0
        for (; e + 8 <= eend; e += 8) {
            int2 sw0 = srcw[e],     sw1 = srcw[e + 1], sw2 = srcw[e + 2], sw3 = srcw[e + 3];
            int2 sw4 = srcw[e + 4], sw5 = srcw[e + 5], sw6 = srcw[e + 6], sw7 = srcw[e + 7];
            float h0 = ldh(sw0.x), h1 = ldh(sw1.x), h2 = ldh(sw2.x), h3 = ldh(sw3.x);
            float h4 = ldh(sw4.x), h5 = ldh(sw5.x), h6 = ldh(sw6.x), h7 = ldh(sw7.x);
            acc = fmaf(__int_as_float(sw0.y), h0, acc);
            acc = fmaf(__int_as_float(sw1.y), h1, acc);
            acc = fmaf(__int_as_float(sw2.y), h2, acc);
            acc = fmaf(__int_as_float(sw3.y), h3, acc);
            acc = fmaf(__int_as_float(sw4.y), h4, acc);
            acc = fmaf(__int_as_float(sw5.y), h5, acc);
            acc = fmaf(__int_as_float(sw6.y), h6, acc);
            acc = fmaf(__int_as_float(sw7.y), h7, acc);
        }
        for (; e + 4 <= eend; e += 4) {
            int2 sw0 = srcw[e], sw1 = srcw[e + 1], sw2 = srcw[e + 2], sw3 = srcw[e + 3];
            float h0 = ldh(sw0.x), h1 = ldh(sw1.x), h2 = ldh(sw2.x), h3 = ldh(sw3.x);
            acc = fmaf(__int_as_float(sw0.y), h0, acc);
            acc = fmaf(__int_as_float(sw1.y), h1, acc);
            acc = fmaf(__int_as_float(sw2.y), h2, acc);
            acc = fmaf(__int_as_float(sw3.y), h3, acc);
        }
        for (; e < eend; e++) {
            int2 sw = srcw[e];
            acc = fmaf(__int_as_float(sw.y), ldh(sw.x), acc);
        }
        __syncthreads();                    // protect aggP from previous node's readers
        if (lane < KIN) aggP[wv][lane] = acc;
        __syncthreads();
        if (wv == 0) {
            float dot = 0.f;
            const float4* a0 = (const float4*)aggP[0];
            const float4* a1 = (const float4*)aggP[1];
#pragma unroll
            for (int k4 = 0; k4 < KIN / 4; k4++) {
                float4 a = a0[k4], b = a1[k4];
                dot = fmaf(a.x + b.x, wreg[4 * k4 + 0], dot);
                dot = fmaf(a.y + b.y, wreg[4 * k4 + 1], dot);
                dot = fmaf(a.z + b.z, wreg[4 * k4 + 2], dot);
                dot = fmaf(a.w + b.w, wreg[4 * k4 + 3], dot);
            }
            float y = fmaxf(fmaf(dot, sc, sh), 0.f);
            if (OUTBF) ((u16*)hout_)[(size_t)i * HDIM + lane] = f2bf_rne(y);
            else       ((float*)hout_)[(size_t)i * HDIM + lane] = y;
        }
    }
}

// ---------------- pooling (4 waves per graph) + 2-layer MLP ----------------
__global__ __launch_bounds__(256) void pool_mlp_k(
    const float* __restrict__ h, const int* __restrict__ batch,
    const float* __restrict__ Wc1, const float* __restrict__ bc1,
    const float* __restrict__ Wc2, const float* __restrict__ bc2,
    float* __restrict__ out, int n) {
    int gidx = blockIdx.x;
    int tid = threadIdx.x;
    int lane = tid & 63;
    int wv = tid >> 6;

    int lo = 0, hi = n;
    while (lo < hi) { int mid = (lo + hi) >> 1; if (batch[mid] < gidx) lo = mid + 1; else hi = mid; }
    int start = lo;
    lo = start; hi = n;
    while (lo < hi) { int mid = (lo + hi) >> 1; if (batch[mid] <= gidx) lo = mid + 1; else hi = mid; }
    int end = lo;

    float sum = 0.f, mx = 0.f;   // h >= 0 post-ReLU
    for (int i = start + wv; i < end; i += 4) {
        float val = h[(size_t)i * HDIM + lane];
        sum += val;
        mx = fmaxf(mx, val);
    }
    __shared__ float ssum[4 * HDIM];
    __shared__ float smax[4 * HDIM];
    __shared__ float pooled[2 * HDIM];
    ssum[wv * HDIM + lane] = sum;
    smax[wv * HDIM + lane] = mx;
    __syncthreads();
    if (wv == 0) {
        float sv = ssum[lane] + ssum[64 + lane] + ssum[128 + lane] + ssum[192 + lane];
        float mm = fmaxf(fmaxf(smax[lane], smax[64 + lane]),
                         fmaxf(smax[128 + lane], smax[192 + lane]));
        int cnt = end - start;
        pooled[lane] = sv / fmaxf((float)cnt, 1.f);
        pooled[HDIM + lane] = mm;
    }
    __syncthreads();
    if (wv == 0) {
        float a = bc1[lane];
#pragma unroll
        for (int k = 0; k < 2 * HDIM; k++) a = fmaf(pooled[k], Wc1[k * HDIM + lane], a);
        a = fmaxf(a, 0.f);
#pragma unroll
        for (int c = 0; c < 2; c++) {
            float vv = a * Wc2[lane * 2 + c];
            for (int off = 32; off; off >>= 1) vv += __shfl_down(vv, off);
            if (lane == 0) out[gidx * 2 + c] = vv + bc2[c];
        }
    }
}

extern "C" void kernel_launch(void* const* d_in, const int* in_sizes, int n_in,
                              void* d_out, int out_size, void* d_ws, size_t ws_size,
                              hipStream_t stream) {
    const float* x    = (const float*)d_in[0];
    const int*   erow = (const int*)d_in[1];
    const int*   ecol = (const int*)d_in[2];
    const int*   batch= (const int*)d_in[3];
    const float* W0   = (const float*)d_in[4];
    const float* b0   = (const float*)d_in[5];
    const float* W1   = (const float*)d_in[6];
    const float* b1   = (const float*)d_in[7];
    const float* W2   = (const float*)d_in[8];
    const float* b2   = (const float*)d_in[9];
    const float* bn_g = (const float*)d_in[10];
    const float* bn_b = (const float*)d_in[11];
    const float* bn_m = (const float*)d_in[12];
    const float* bn_v = (const float*)d_in[13];
    const float* Wc1  = (const float*)d_in[14];
    const float* bc1  = (const float*)d_in[15];
    const float* Wc2  = (const float*)d_in[16];
    const float* bc2  = (const float*)d_in[17];
    float* out = (float*)d_out;

    const int N = in_sizes[3];
    const int E = in_sizes[1];
    const int G = out_size / 2;
    const int INR = in_sizes[0] / N;    // 26

    char* ws = (char*)d_ws;
    size_t off = 0;
    auto alloc = [&](size_t bytes) -> void* {
        void* p = ws + off;
        off += (bytes + 255) & ~(size_t)255;
        return p;
    };
    int*   cnt    = (int*)alloc((size_t)N * 4);
    float* dinv   = (float*)alloc((size_t)N * 4);
    int*   offs   = (int*)alloc((size_t)(N + 1) * 4);
    int*   cursor = (int*)alloc((size_t)N * 4);
    int*   bsum   = (int*)alloc(1024);
    int*   ctr    = (int*)alloc(32);
    int2*  srcw   = (int2*)alloc((size_t)E * 8 + 256);
    void*  bufA   = alloc((size_t)N * HDIM * 4);   // h1 (bf16) then h3 (f32)
    void*  bufB   = alloc((size_t)N * HDIM * 4);   // xp (f32 [N][32]) then h2 (bf16)
    (void)ws_size;

    // ---- build gcn_norm + CSR transpose ----
    hipMemsetAsync(cnt, 0, (size_t)N * 4, stream);
    hipMemsetAsync(ctr, 0, 32, stream);
    count_edges_k<<<(E + 255) / 256, 256, 0, stream>>>(ecol, cnt, E);
    int nb = (N + 1023) / 1024;
    scan_partial_k<<<nb, 256, 0, stream>>>(cnt, offs, bsum, N);
    scan_add_k<<<(N + 255) / 256, 256, 0, stream>>>(cnt, offs, bsum, nb, cursor, dinv, N, E);
    int nchunks = (E + 255) / 256;
    int fblocks = 2048;
    fillpad_k<<<fblocks, 256, 0, stream>>>(erow, ecol, dinv, cursor, srcw, E, N,
                                           x, (float*)bufB, INR, N * 32, ctr, nchunks, fblocks);

    int cgrid = (N + MNODES - 1) / MNODES;
    // ---- layer 0: xp f32 [N][32] -> h1 bf16 ----
    conv_k<32, false, true><<<cgrid, 128, 0, stream>>>(bufB, offs, srcw, dinv, W0, INR, b0,
        bn_g + 0, bn_b + 0, bn_m + 0, bn_v + 0, bufA, N);
    // ---- layer 1: h1 bf16 -> h2 bf16 ----
    conv_k<64, true, true><<<cgrid, 128, 0, stream>>>(bufA, offs, srcw, dinv, W1, 64, b1,
        bn_g + 64, bn_b + 64, bn_m + 64, bn_v + 64, bufB, N);
    // ---- layer 2: h2 bf16 -> h3 f32 ----
    conv_k<64, true, false><<<cgrid, 128, 0, stream>>>(bufB, offs, srcw, dinv, W2, 64, b2,
        bn_g + 128, bn_b + 128, bn_m + 128, bn_v + 128, bufA, N);

    // ---- pool + MLP ----
    pool_mlp_k<<<G, 256, 0, stream>>>((const float*)bufA, batch, Wc1, bc1, Wc2, bc2, out, N);
}

// Round 10
// 597.426 us; speedup vs baseline: 2.2874x; 2.2874x over previous
//
#include <hip/hip_runtime.h>

#define HDIM 64
#define EPSBN 1e-5f
#define MNODES 8
#define ECAP 512

typedef unsigned short u16;

__device__ __forceinline__ float bf2f(u16 b) {
    return __uint_as_float(((unsigned)b) << 16);
}
__device__ __forceinline__ u16 f2bf_rne(float f) {
    unsigned u = __float_as_uint(f);
    u += 0x7FFFu + ((u >> 16) & 1u);      // round-to-nearest-even
    return (u16)(u >> 16);
}

// ---------------- degree count ----------------
__global__ void count_edges_k(const int* __restrict__ col, int* __restrict__ cnt, int E) {
    int e = blockIdx.x * blockDim.x + threadIdx.x;
    if (e < E) atomicAdd(&cnt[col[e]], 1);
}

// ---------------- exclusive scan of cnt -> offs ----------------
__global__ void scan_partial_k(const int* __restrict__ cnt, int* __restrict__ offs,
                               int* __restrict__ bsum, int n) {
    __shared__ int lds[256];
    int tid = threadIdx.x;
    int base = blockIdx.x * 1024 + tid * 4;
    int v0 = (base + 0 < n) ? cnt[base + 0] : 0;
    int v1 = (base + 1 < n) ? cnt[base + 1] : 0;
    int v2 = (base + 2 < n) ? cnt[base + 2] : 0;
    int v3 = (base + 3 < n) ? cnt[base + 3] : 0;
    int tsum = v0 + v1 + v2 + v3;
    lds[tid] = tsum;
    __syncthreads();
    for (int off = 1; off < 256; off <<= 1) {
        int t = (tid >= off) ? lds[tid - off] : 0;
        __syncthreads();
        lds[tid] += t;
        __syncthreads();
    }
    int excl = lds[tid] - tsum;
    if (tid == 255) bsum[blockIdx.x] = lds[255];
    int run = excl;
    if (base + 0 < n) { offs[base + 0] = run; } run += v0;
    if (base + 1 < n) { offs[base + 1] = run; } run += v1;
    if (base + 2 < n) { offs[base + 2] = run; } run += v2;
    if (base + 3 < n) { offs[base + 3] = run; }
}

// adds block bases (re-scans <=256 block sums in-block), writes cursor + dinv
__global__ void scan_add_k(const int* __restrict__ cnt, int* __restrict__ offs,
                           const int* __restrict__ bsum, int nb,
                           int* __restrict__ cursor, float* __restrict__ dinv,
                           int n, int Etot) {
    __shared__ int lds[256];
    int tid = threadIdx.x;
    int v = (tid < nb) ? bsum[tid] : 0;
    lds[tid] = v;
    __syncthreads();
    for (int off = 1; off < 256; off <<= 1) {
        int t = (tid >= off) ? lds[tid - off] : 0;
        __syncthreads();
        lds[tid] += t;
        __syncthreads();
    }
    int excl = lds[tid] - v;
    __syncthreads();
    lds[tid] = excl;
    __syncthreads();

    int i = blockIdx.x * blockDim.x + tid;
    if (i < n) {
        int o = offs[i] + lds[i >> 10];
        offs[i] = o;
        cursor[i] = o;
        dinv[i] = rsqrtf((float)cnt[i] + 1.0f);   // +1 for self-loop
    }
    if (i == 0) offs[n] = Etot;
}

// ---------------- CSR fill (R8-proven) + bf16 x padding, fused ----------------
__global__ void fillpad_k(const int* __restrict__ row, const int* __restrict__ col,
                          const float* __restrict__ dinv, int* __restrict__ cursor,
                          int2* __restrict__ srcw, int E, int N,
                          const float* __restrict__ x, u16* __restrict__ xp,
                          int INR, int padTot) {
    int bid = blockIdx.x, tid = threadIdx.x;
    int pidx = bid * 256 + tid;
    if (pidx < padTot) {
        int i = pidx >> 5, k = pidx & 31;
        xp[pidx] = (k < INR) ? f2bf_rne(x[i * INR + k]) : (u16)0;
    }
    int xcd = bid & 7;
    int chunk = bid >> 3;
    int e = chunk * 256 + tid;
    if (e >= E) return;
    int c = col[e];
    int owner = (int)(((unsigned long long)c * 8ull) / (unsigned)N);
    if (owner != xcd) return;
    int r = row[e];
    float w = dinv[r] * dinv[c];
    int pos = atomicAdd(&cursor[c], 1);
    srcw[pos] = make_int2(r, __float_as_int(w));
}

// ---------------- fused conv: LDS-staged edges + gather + dense + BN + ReLU ----------------
// 1 wave/block, MNODES nodes serial, lane = output feature; features bf16 in.
// Per node-chunk: stage <=ECAP edges into LDS with a coalesced 64-lane vector
// load (replaces the serial scalar-load chain), then 8-wide unrolled gather
// reading edge data from LDS (ds_read_b64 broadcast, independent addresses).
template <int KIN, bool OUTBF>
__global__ __launch_bounds__(64) void conv_k(
    const u16* __restrict__ hb, const int* __restrict__ offs,
    const int2* __restrict__ srcw, const float* __restrict__ dinv,
    const float* __restrict__ W, int KINR,
    const float* __restrict__ bias, const float* __restrict__ g,
    const float* __restrict__ bb, const float* __restrict__ m,
    const float* __restrict__ v, void* __restrict__ hout_, int n) {
    int lane = threadIdx.x;
    float wreg[KIN];
#pragma unroll
    for (int k = 0; k < KIN; k++) wreg[k] = (k < KINR) ? W[k * HDIM + lane] : 0.f;
    const float sc = g[lane] * rsqrtf(v[lane] + EPSBN);
    const float sh = (bias[lane] - m[lane]) * sc + bb[lane];

    __shared__ float agg[KIN];
    __shared__ int2 ebuf[ECAP];

    const int feat = lane & (KIN - 1);
    auto ldh = [&](int node) -> float {
        return bf2f(hb[(size_t)node * KIN + feat]);
    };

    int i0 = blockIdx.x * MNODES;
    for (int j = 0; j < MNODES; j++) {
        int i = i0 + j;
        if (i >= n) break;                  // wave-uniform
        float di = dinv[i];
        float acc = ldh(i) * (di * di);     // self-loop
        int e0 = offs[i], s1 = offs[i + 1];
        for (int cb = e0; cb < s1; cb += ECAP) {
            int M = min(ECAP, s1 - cb);
            __syncthreads();                // 1 wave -> waitcnt only
            for (int k = lane; k < M; k += 64) ebuf[k] = srcw[cb + k];  // coalesced
            __syncthreads();
            int k = 0;
            for (; k + 8 <= M; k += 8) {
                int2 sw0 = ebuf[k],     sw1 = ebuf[k + 1], sw2 = ebuf[k + 2], sw3 = ebuf[k + 3];
                int2 sw4 = ebuf[k + 4], sw5 = ebuf[k + 5], sw6 = ebuf[k + 6], sw7 = ebuf[k + 7];
                float h0 = ldh(sw0.x), h1 = ldh(sw1.x), h2 = ldh(sw2.x), h3 = ldh(sw3.x);
                float h4 = ldh(sw4.x), h5 = ldh(sw5.x), h6 = ldh(sw6.x), h7 = ldh(sw7.x);
                acc = fmaf(__int_as_float(sw0.y), h0, acc);
                acc = fmaf(__int_as_float(sw1.y), h1, acc);
                acc = fmaf(__int_as_float(sw2.y), h2, acc);
                acc = fmaf(__int_as_float(sw3.y), h3, acc);
                acc = fmaf(__int_as_float(sw4.y), h4, acc);
                acc = fmaf(__int_as_float(sw5.y), h5, acc);
                acc = fmaf(__int_as_float(sw6.y), h6, acc);
                acc = fmaf(__int_as_float(sw7.y), h7, acc);
            }
            for (; k + 4 <= M; k += 4) {
                int2 sw0 = ebuf[k], sw1 = ebuf[k + 1], sw2 = ebuf[k + 2], sw3 = ebuf[k + 3];
                float h0 = ldh(sw0.x), h1 = ldh(sw1.x), h2 = ldh(sw2.x), h3 = ldh(sw3.x);
                acc = fmaf(__int_as_float(sw0.y), h0, acc);
                acc = fmaf(__int_as_float(sw1.y), h1, acc);
                acc = fmaf(__int_as_float(sw2.y), h2, acc);
                acc = fmaf(__int_as_float(sw3.y), h3, acc);
            }
            for (; k < M; k++) {
                int2 sw = ebuf[k];
                acc = fmaf(__int_as_float(sw.y), ldh(sw.x), acc);
            }
        }
        __syncthreads();                    // protect agg from previous iteration readers
        if (lane < KIN) agg[lane] = acc;
        __syncthreads();
        float dot = 0.f;
        const float4* aggv = (const float4*)agg;
#pragma unroll
        for (int k4 = 0; k4 < KIN / 4; k4++) {
            float4 a = aggv[k4];
            dot = fmaf(a.x, wreg[4 * k4 + 0], dot);
            dot = fmaf(a.y, wreg[4 * k4 + 1], dot);
            dot = fmaf(a.z, wreg[4 * k4 + 2], dot);
            dot = fmaf(a.w, wreg[4 * k4 + 3], dot);
        }
        float y = fmaxf(fmaf(dot, sc, sh), 0.f);
        if (OUTBF) ((u16*)hout_)[(size_t)i * HDIM + lane] = f2bf_rne(y);
        else       ((float*)hout_)[(size_t)i * HDIM + lane] = y;
    }
}

// ---------------- pooling (4 waves per graph) + 2-layer MLP ----------------
__global__ __launch_bounds__(256) void pool_mlp_k(
    const float* __restrict__ h, const int* __restrict__ batch,
    const float* __restrict__ Wc1, const float* __restrict__ bc1,
    const float* __restrict__ Wc2, const float* __restrict__ bc2,
    float* __restrict__ out, int n) {
    int gidx = blockIdx.x;
    int tid = threadIdx.x;
    int lane = tid & 63;
    int wv = tid >> 6;

    int lo = 0, hi = n;
    while (lo < hi) { int mid = (lo + hi) >> 1; if (batch[mid] < gidx) lo = mid + 1; else hi = mid; }
    int start = lo;
    lo = start; hi = n;
    while (lo < hi) { int mid = (lo + hi) >> 1; if (batch[mid] <= gidx) lo = mid + 1; else hi = mid; }
    int end = lo;

    float sum = 0.f, mx = 0.f;   // h >= 0 post-ReLU
    for (int i = start + wv; i < end; i += 4) {
        float val = h[(size_t)i * HDIM + lane];
        sum += val;
        mx = fmaxf(mx, val);
    }
    __shared__ float ssum[4 * HDIM];
    __shared__ float smax[4 * HDIM];
    __shared__ float pooled[2 * HDIM];
    ssum[wv * HDIM + lane] = sum;
    smax[wv * HDIM + lane] = mx;
    __syncthreads();
    if (wv == 0) {
        float sv = ssum[lane] + ssum[64 + lane] + ssum[128 + lane] + ssum[192 + lane];
        float mm = fmaxf(fmaxf(smax[lane], smax[64 + lane]),
                         fmaxf(smax[128 + lane], smax[192 + lane]));
        int cnt = end - start;
        pooled[lane] = sv / fmaxf((float)cnt, 1.f);
        pooled[HDIM + lane] = mm;
    }
    __syncthreads();
    if (wv == 0) {
        float a = bc1[lane];
#pragma unroll
        for (int k = 0; k < 2 * HDIM; k++) a = fmaf(pooled[k], Wc1[k * HDIM + lane], a);
        a = fmaxf(a, 0.f);
#pragma unroll
        for (int c = 0; c < 2; c++) {
            float vv = a * Wc2[lane * 2 + c];
            for (int off = 32; off; off >>= 1) vv += __shfl_down(vv, off);
            if (lane == 0) out[gidx * 2 + c] = vv + bc2[c];
        }
    }
}

extern "C" void kernel_launch(void* const* d_in, const int* in_sizes, int n_in,
                              void* d_out, int out_size, void* d_ws, size_t ws_size,
                              hipStream_t stream) {
    const float* x    = (const float*)d_in[0];
    const int*   erow = (const int*)d_in[1];
    const int*   ecol = (const int*)d_in[2];
    const int*   batch= (const int*)d_in[3];
    const float* W0   = (const float*)d_in[4];
    const float* b0   = (const float*)d_in[5];
    const float* W1   = (const float*)d_in[6];
    const float* b1   = (const float*)d_in[7];
    const float* W2   = (const float*)d_in[8];
    const float* b2   = (const float*)d_in[9];
    const float* bn_g = (const float*)d_in[10];
    const float* bn_b = (const float*)d_in[11];
    const float* bn_m = (const float*)d_in[12];
    const float* bn_v = (const float*)d_in[13];
    const float* Wc1  = (const float*)d_in[14];
    const float* bc1  = (const float*)d_in[15];
    const float* Wc2  = (const float*)d_in[16];
    const float* bc2  = (const float*)d_in[17];
    float* out = (float*)d_out;

    const int N = in_sizes[3];
    const int E = in_sizes[1];
    const int G = out_size / 2;
    const int INR = in_sizes[0] / N;    // 26

    char* ws = (char*)d_ws;
    size_t off = 0;
    auto alloc = [&](size_t bytes) -> void* {
        void* p = ws + off;
        off += (bytes + 255) & ~(size_t)255;
        return p;
    };
    int*   cnt    = (int*)alloc((size_t)N * 4);
    float* dinv   = (float*)alloc((size_t)N * 4);
    int*   offs   = (int*)alloc((size_t)(N + 1) * 4);
    int*   cursor = (int*)alloc((size_t)N * 4);
    int*   bsum   = (int*)alloc(1024);
    int2*  srcw   = (int2*)alloc((size_t)E * 8 + 256);
    void*  bufA   = alloc((size_t)N * HDIM * 4);   // h1 (bf16) then h3 (f32)
    void*  bufB   = alloc((size_t)N * HDIM * 4);   // xp (bf16 [N][32]) then h2 (bf16)
    (void)ws_size;

    // ---- build gcn_norm + CSR transpose ----
    hipMemsetAsync(cnt, 0, (size_t)N * 4, stream);
    count_edges_k<<<(E + 255) / 256, 256, 0, stream>>>(ecol, cnt, E);
    int nb = (N + 1023) / 1024;
    scan_partial_k<<<nb, 256, 0, stream>>>(cnt, offs, bsum, N);
    scan_add_k<<<(N + 255) / 256, 256, 0, stream>>>(cnt, offs, bsum, nb, cursor, dinv, N, E);
    int chunks = (E + 255) / 256;
    fillpad_k<<<chunks * 8, 256, 0, stream>>>(erow, ecol, dinv, cursor, srcw, E, N,
                                              x, (u16*)bufB, INR, N * 32);

    int cgrid = (N + MNODES - 1) / MNODES;
    // ---- layer 0: xp bf16 [N][32] -> h1 bf16 ----
    conv_k<32, true><<<cgrid, 64, 0, stream>>>((const u16*)bufB, offs, srcw, dinv, W0, INR, b0,
        bn_g + 0, bn_b + 0, bn_m + 0, bn_v + 0, bufA, N);
    // ---- layer 1: h1 bf16 -> h2 bf16 ----
    conv_k<64, true><<<cgrid, 64, 0, stream>>>((const u16*)bufA, offs, srcw, dinv, W1, 64, b1,
        bn_g + 64, bn_b + 64, bn_m + 64, bn_v + 64, bufB, N);
    // ---- layer 2: h2 bf16 -> h3 f32 ----
    conv_k<64, false><<<cgrid, 64, 0, stream>>>((const u16*)bufB, offs, srcw, dinv, W2, 64, b2,
        bn_g + 128, bn_b + 128, bn_m + 128, bn_v + 128, bufA, N);

    // ---- pool + MLP ----
    pool_mlp_k<<<G, 256, 0, stream>>>((const float*)bufA, batch, Wc1, bc1, Wc2, bc2, out, N);
}

// Round 11
// 444.091 us; speedup vs baseline: 3.0772x; 1.3453x over previous
//
#include <hip/hip_runtime.h>

#define HDIM 64
#define EPSBN 1e-5f
#define MNODES 8

typedef unsigned short u16;

__device__ __forceinline__ float bf2f(u16 b) {
    return __uint_as_float(((unsigned)b) << 16);
}
__device__ __forceinline__ u16 f2bf_rne(float f) {
    unsigned u = __float_as_uint(f);
    u += 0x7FFFu + ((u >> 16) & 1u);      // round-to-nearest-even
    return (u16)(u >> 16);
}

// ---------------- degree count ----------------
__global__ void count_edges_k(const int* __restrict__ col, int* __restrict__ cnt, int E) {
    int e = blockIdx.x * blockDim.x + threadIdx.x;
    if (e < E) atomicAdd(&cnt[col[e]], 1);
}

// ---------------- exclusive scan of cnt -> offs ----------------
__global__ void scan_partial_k(const int* __restrict__ cnt, int* __restrict__ offs,
                               int* __restrict__ bsum, int n) {
    __shared__ int lds[256];
    int tid = threadIdx.x;
    int base = blockIdx.x * 1024 + tid * 4;
    int v0 = (base + 0 < n) ? cnt[base + 0] : 0;
    int v1 = (base + 1 < n) ? cnt[base + 1] : 0;
    int v2 = (base + 2 < n) ? cnt[base + 2] : 0;
    int v3 = (base + 3 < n) ? cnt[base + 3] : 0;
    int tsum = v0 + v1 + v2 + v3;
    lds[tid] = tsum;
    __syncthreads();
    for (int off = 1; off < 256; off <<= 1) {
        int t = (tid >= off) ? lds[tid - off] : 0;
        __syncthreads();
        lds[tid] += t;
        __syncthreads();
    }
    int excl = lds[tid] - tsum;
    if (tid == 255) bsum[blockIdx.x] = lds[255];
    int run = excl;
    if (base + 0 < n) { offs[base + 0] = run; } run += v0;
    if (base + 1 < n) { offs[base + 1] = run; } run += v1;
    if (base + 2 < n) { offs[base + 2] = run; } run += v2;
    if (base + 3 < n) { offs[base + 3] = run; }
}

// adds block bases (re-scans <=256 block sums in-block), writes cursor + dinv
__global__ void scan_add_k(const int* __restrict__ cnt, int* __restrict__ offs,
                           const int* __restrict__ bsum, int nb,
                           int* __restrict__ cursor, float* __restrict__ dinv,
                           int n, int Etot) {
    __shared__ int lds[256];
    int tid = threadIdx.x;
    int v = (tid < nb) ? bsum[tid] : 0;
    lds[tid] = v;
    __syncthreads();
    for (int off = 1; off < 256; off <<= 1) {
        int t = (tid >= off) ? lds[tid - off] : 0;
        __syncthreads();
        lds[tid] += t;
        __syncthreads();
    }
    int excl = lds[tid] - v;
    __syncthreads();
    lds[tid] = excl;
    __syncthreads();

    int i = blockIdx.x * blockDim.x + tid;
    if (i < n) {
        int o = offs[i] + lds[i >> 10];
        offs[i] = o;
        cursor[i] = o;
        dinv[i] = rsqrtf((float)cnt[i] + 1.0f);   // +1 for self-loop
    }
    if (i == 0) offs[n] = Etot;
}

// ---------------- CSR fill (R8-proven) + bf16 x padding, fused ----------------
__global__ void fillpad_k(const int* __restrict__ row, const int* __restrict__ col,
                          const float* __restrict__ dinv, int* __restrict__ cursor,
                          int2* __restrict__ srcw, int E, int N,
                          const float* __restrict__ x, u16* __restrict__ xp,
                          int INR, int padTot) {
    int bid = blockIdx.x, tid = threadIdx.x;
    int pidx = bid * 256 + tid;
    if (pidx < padTot) {
        int i = pidx >> 5, k = pidx & 31;
        xp[pidx] = (k < INR) ? f2bf_rne(x[i * INR + k]) : (u16)0;
    }
    int xcd = bid & 7;
    int chunk = bid >> 3;
    int e = chunk * 256 + tid;
    if (e >= E) return;
    int c = col[e];
    int owner = (int)(((unsigned long long)c * 8ull) / (unsigned)N);
    if (owner != xcd) return;
    int r = row[e];
    float w = dinv[r] * dinv[c];
    int pos = atomicAdd(&cursor[c], 1);
    srcw[pos] = make_int2(r, __float_as_int(w));
}

// ---------------- fused conv: 2-node-interleaved gather + dense + BN + ReLU ----------------
// 1 wave/block, MNODES nodes as pairs; lane = output feature; features bf16.
// Two independent edge streams (node A, node B) interleaved 4+4 per iteration:
// 2 independent s_load+gather+fma chains in flight per wave at all times.
template <int KIN, bool OUTBF>
__global__ __launch_bounds__(64) void conv_k(
    const u16* __restrict__ hb, const int* __restrict__ offs,
    const int2* __restrict__ srcw, const float* __restrict__ dinv,
    const float* __restrict__ W, int KINR,
    const float* __restrict__ bias, const float* __restrict__ g,
    const float* __restrict__ bb, const float* __restrict__ m,
    const float* __restrict__ v, void* __restrict__ hout_, int n) {
    int lane = threadIdx.x;
    float wreg[KIN];
#pragma unroll
    for (int k = 0; k < KIN; k++) wreg[k] = (k < KINR) ? W[k * HDIM + lane] : 0.f;
    const float sc = g[lane] * rsqrtf(v[lane] + EPSBN);
    const float sh = (bias[lane] - m[lane]) * sc + bb[lane];

    __shared__ float agg2[2][KIN];

    const int feat = lane & (KIN - 1);
    auto ldh = [&](int node) -> float {
        return bf2f(hb[(size_t)node * KIN + feat]);
    };

    int i0 = blockIdx.x * MNODES;
    for (int t = 0; t < MNODES / 2; t++) {
        int iA = i0 + 2 * t, iB = iA + 1;
        if (iA >= n) break;                 // wave-uniform
        bool hasB = (iB < n);
        float dA = dinv[iA];
        float accA = ldh(iA) * (dA * dA);
        float accB = 0.f;
        int eA = offs[iA], endA = offs[iA + 1];
        int eB = 0, endB = 0;
        if (hasB) {
            float dB = dinv[iB];
            accB = ldh(iB) * (dB * dB);
            eB = offs[iB + 0]; endB = offs[iB + 1];
            // note: eB = endA (contiguous CSR) but keep general
            eB = endA; // offs[iB]
        }
        // interleaved main loop: 4 edges from A + 4 from B per iteration
        while (eA + 4 <= endA && eB + 4 <= endB) {
            int2 a0 = srcw[eA], a1 = srcw[eA + 1], a2 = srcw[eA + 2], a3 = srcw[eA + 3];
            int2 b0 = srcw[eB], b1 = srcw[eB + 1], b2 = srcw[eB + 2], b3 = srcw[eB + 3];
            float ha0 = ldh(a0.x), ha1 = ldh(a1.x), ha2 = ldh(a2.x), ha3 = ldh(a3.x);
            float hb0 = ldh(b0.x), hb1 = ldh(b1.x), hb2 = ldh(b2.x), hb3 = ldh(b3.x);
            accA = fmaf(__int_as_float(a0.y), ha0, accA);
            accA = fmaf(__int_as_float(a1.y), ha1, accA);
            accA = fmaf(__int_as_float(a2.y), ha2, accA);
            accA = fmaf(__int_as_float(a3.y), ha3, accA);
            accB = fmaf(__int_as_float(b0.y), hb0, accB);
            accB = fmaf(__int_as_float(b1.y), hb1, accB);
            accB = fmaf(__int_as_float(b2.y), hb2, accB);
            accB = fmaf(__int_as_float(b3.y), hb3, accB);
            eA += 4; eB += 4;
        }
        // drain A (8/4/1-wide, R7-proven shape)
        for (; eA + 8 <= endA; eA += 8) {
            int2 s0 = srcw[eA],     s1 = srcw[eA + 1], s2 = srcw[eA + 2], s3 = srcw[eA + 3];
            int2 s4 = srcw[eA + 4], s5 = srcw[eA + 5], s6 = srcw[eA + 6], s7 = srcw[eA + 7];
            float h0 = ldh(s0.x), h1 = ldh(s1.x), h2 = ldh(s2.x), h3 = ldh(s3.x);
            float h4 = ldh(s4.x), h5 = ldh(s5.x), h6 = ldh(s6.x), h7 = ldh(s7.x);
            accA = fmaf(__int_as_float(s0.y), h0, accA);
            accA = fmaf(__int_as_float(s1.y), h1, accA);
            accA = fmaf(__int_as_float(s2.y), h2, accA);
            accA = fmaf(__int_as_float(s3.y), h3, accA);
            accA = fmaf(__int_as_float(s4.y), h4, accA);
            accA = fmaf(__int_as_float(s5.y), h5, accA);
            accA = fmaf(__int_as_float(s6.y), h6, accA);
            accA = fmaf(__int_as_float(s7.y), h7, accA);
        }
        for (; eA + 4 <= endA; eA += 4) {
            int2 s0 = srcw[eA], s1 = srcw[eA + 1], s2 = srcw[eA + 2], s3 = srcw[eA + 3];
            float h0 = ldh(s0.x), h1 = ldh(s1.x), h2 = ldh(s2.x), h3 = ldh(s3.x);
            accA = fmaf(__int_as_float(s0.y), h0, accA);
            accA = fmaf(__int_as_float(s1.y), h1, accA);
            accA = fmaf(__int_as_float(s2.y), h2, accA);
            accA = fmaf(__int_as_float(s3.y), h3, accA);
        }
        for (; eA < endA; eA++) {
            int2 s0 = srcw[eA];
            accA = fmaf(__int_as_float(s0.y), ldh(s0.x), accA);
        }
        // drain B
        for (; eB + 8 <= endB; eB += 8) {
            int2 s0 = srcw[eB],     s1 = srcw[eB + 1], s2 = srcw[eB + 2], s3 = srcw[eB + 3];
            int2 s4 = srcw[eB + 4], s5 = srcw[eB + 5], s6 = srcw[eB + 6], s7 = srcw[eB + 7];
            float h0 = ldh(s0.x), h1 = ldh(s1.x), h2 = ldh(s2.x), h3 = ldh(s3.x);
            float h4 = ldh(s4.x), h5 = ldh(s5.x), h6 = ldh(s6.x), h7 = ldh(s7.x);
            accB = fmaf(__int_as_float(s0.y), h0, accB);
            accB = fmaf(__int_as_float(s1.y), h1, accB);
            accB = fmaf(__int_as_float(s2.y), h2, accB);
            accB = fmaf(__int_as_float(s3.y), h3, accB);
            accB = fmaf(__int_as_float(s4.y), h4, accB);
            accB = fmaf(__int_as_float(s5.y), h5, accB);
            accB = fmaf(__int_as_float(s6.y), h6, accB);
            accB = fmaf(__int_as_float(s7.y), h7, accB);
        }
        for (; eB + 4 <= endB; eB += 4) {
            int2 s0 = srcw[eB], s1 = srcw[eB + 1], s2 = srcw[eB + 2], s3 = srcw[eB + 3];
            float h0 = ldh(s0.x), h1 = ldh(s1.x), h2 = ldh(s2.x), h3 = ldh(s3.x);
            accB = fmaf(__int_as_float(s0.y), h0, accB);
            accB = fmaf(__int_as_float(s1.y), h1, accB);
            accB = fmaf(__int_as_float(s2.y), h2, accB);
            accB = fmaf(__int_as_float(s3.y), h3, accB);
        }
        for (; eB < endB; eB++) {
            int2 s0 = srcw[eB];
            accB = fmaf(__int_as_float(s0.y), ldh(s0.x), accB);
        }

        __syncthreads();                    // protect agg2 from previous pair's readers
        if (lane < KIN) { agg2[0][lane] = accA; agg2[1][lane] = accB; }
        __syncthreads();
        // dense for A then B
        for (int q = 0; q < 2; q++) {
            int i = iA + q;
            if (i >= n) break;
            float dot = 0.f;
            const float4* aggv = (const float4*)agg2[q];
#pragma unroll
            for (int k4 = 0; k4 < KIN / 4; k4++) {
                float4 a = aggv[k4];
                dot = fmaf(a.x, wreg[4 * k4 + 0], dot);
                dot = fmaf(a.y, wreg[4 * k4 + 1], dot);
                dot = fmaf(a.z, wreg[4 * k4 + 2], dot);
                dot = fmaf(a.w, wreg[4 * k4 + 3], dot);
            }
            float y = fmaxf(fmaf(dot, sc, sh), 0.f);
            if (OUTBF) ((u16*)hout_)[(size_t)i * HDIM + lane] = f2bf_rne(y);
            else       ((float*)hout_)[(size_t)i * HDIM + lane] = y;
        }
    }
}

// ---------------- pooling (4 waves per graph) + 2-layer MLP ----------------
__global__ __launch_bounds__(256) void pool_mlp_k(
    const float* __restrict__ h, const int* __restrict__ batch,
    const float* __restrict__ Wc1, const float* __restrict__ bc1,
    const float* __restrict__ Wc2, const float* __restrict__ bc2,
    float* __restrict__ out, int n) {
    int gidx = blockIdx.x;
    int tid = threadIdx.x;
    int lane = tid & 63;
    int wv = tid >> 6;

    int lo = 0, hi = n;
    while (lo < hi) { int mid = (lo + hi) >> 1; if (batch[mid] < gidx) lo = mid + 1; else hi = mid; }
    int start = lo;
    lo = start; hi = n;
    while (lo < hi) { int mid = (lo + hi) >> 1; if (batch[mid] <= gidx) lo = mid + 1; else hi = mid; }
    int end = lo;

    float sum = 0.f, mx = 0.f;   // h >= 0 post-ReLU
    for (int i = start + wv; i < end; i += 4) {
        float val = h[(size_t)i * HDIM + lane];
        sum += val;
        mx = fmaxf(mx, val);
    }
    __shared__ float ssum[4 * HDIM];
    __shared__ float smax[4 * HDIM];
    __shared__ float pooled[2 * HDIM];
    ssum[wv * HDIM + lane] = sum;
    smax[wv * HDIM + lane] = mx;
    __syncthreads();
    if (wv == 0) {
        float sv = ssum[lane] + ssum[64 + lane] + ssum[128 + lane] + ssum[192 + lane];
        float mm = fmaxf(fmaxf(smax[lane], smax[64 + lane]),
                         fmaxf(smax[128 + lane], smax[192 + lane]));
        int cnt = end - start;
        pooled[lane] = sv / fmaxf((float)cnt, 1.f);
        pooled[HDIM + lane] = mm;
    }
    __syncthreads();
    if (wv == 0) {
        float a = bc1[lane];
#pragma unroll
        for (int k = 0; k < 2 * HDIM; k++) a = fmaf(pooled[k], Wc1[k * HDIM + lane], a);
        a = fmaxf(a, 0.f);
#pragma unroll
        for (int c = 0; c < 2; c++) {
            float vv = a * Wc2[lane * 2 + c];
            for (int off = 32; off; off >>= 1) vv += __shfl_down(vv, off);
            if (lane == 0) out[gidx * 2 + c] = vv + bc2[c];
        }
    }
}

extern "C" void kernel_launch(void* const* d_in, const int* in_sizes, int n_in,
                              void* d_out, int out_size, void* d_ws, size_t ws_size,
                              hipStream_t stream) {
    const float* x    = (const float*)d_in[0];
    const int*   erow = (const int*)d_in[1];
    const int*   ecol = (const int*)d_in[2];
    const int*   batch= (const int*)d_in[3];
    const float* W0   = (const float*)d_in[4];
    const float* b0   = (const float*)d_in[5];
    const float* W1   = (const float*)d_in[6];
    const float* b1   = (const float*)d_in[7];
    const float* W2   = (const float*)d_in[8];
    const float* b2   = (const float*)d_in[9];
    const float* bn_g = (const float*)d_in[10];
    const float* bn_b = (const float*)d_in[11];
    const float* bn_m = (const float*)d_in[12];
    const float* bn_v = (const float*)d_in[13];
    const float* Wc1  = (const float*)d_in[14];
    const float* bc1  = (const float*)d_in[15];
    const float* Wc2  = (const float*)d_in[16];
    const float* bc2  = (const float*)d_in[17];
    float* out = (float*)d_out;

    const int N = in_sizes[3];
    const int E = in_sizes[1];
    const int G = out_size / 2;
    const int INR = in_sizes[0] / N;    // 26

    char* ws = (char*)d_ws;
    size_t off = 0;
    auto alloc = [&](size_t bytes) -> void* {
        void* p = ws + off;
        off += (bytes + 255) & ~(size_t)255;
        return p;
    };
    int*   cnt    = (int*)alloc((size_t)N * 4);
    float* dinv   = (float*)alloc((size_t)N * 4);
    int*   offs   = (int*)alloc((size_t)(N + 1) * 4);
    int*   cursor = (int*)alloc((size_t)N * 4);
    int*   bsum   = (int*)alloc(1024);
    int2*  srcw   = (int2*)alloc((size_t)E * 8 + 256);
    void*  bufA   = alloc((size_t)N * HDIM * 4);   // h1 (bf16) then h3 (f32)
    void*  bufB   = alloc((size_t)N * HDIM * 4);   // xp (bf16 [N][32]) then h2 (bf16)
    (void)ws_size;

    // ---- build gcn_norm + CSR transpose ----
    hipMemsetAsync(cnt, 0, (size_t)N * 4, stream);
    count_edges_k<<<(E + 255) / 256, 256, 0, stream>>>(ecol, cnt, E);
    int nb = (N + 1023) / 1024;
    scan_partial_k<<<nb, 256, 0, stream>>>(cnt, offs, bsum, N);
    scan_add_k<<<(N + 255) / 256, 256, 0, stream>>>(cnt, offs, bsum, nb, cursor, dinv, N, E);
    int chunks = (E + 255) / 256;
    fillpad_k<<<chunks * 8, 256, 0, stream>>>(erow, ecol, dinv, cursor, srcw, E, N,
                                              x, (u16*)bufB, INR, N * 32);

    int cgrid = (N + MNODES - 1) / MNODES;
    // ---- layer 0: xp bf16 [N][32] -> h1 bf16 ----
    conv_k<32, true><<<cgrid, 64, 0, stream>>>((const u16*)bufB, offs, srcw, dinv, W0, INR, b0,
        bn_g + 0, bn_b + 0, bn_m + 0, bn_v + 0, bufA, N);
    // ---- layer 1: h1 bf16 -> h2 bf16 ----
    conv_k<64, true><<<cgrid, 64, 0, stream>>>((const u16*)bufA, offs, srcw, dinv, W1, 64, b1,
        bn_g + 64, bn_b + 64, bn_m + 64, bn_v + 64, bufB, N);
    // ---- layer 2: h2 bf16 -> h3 f32 ----
    conv_k<64, false><<<cgrid, 64, 0, stream>>>((const u16*)bufB, offs, srcw, dinv, W2, 64, b2,
        bn_g + 128, bn_b + 128, bn_m + 128, bn_v + 128, bufA, N);

    // ---- pool + MLP ----
    pool_mlp_k<<<G, 256, 0, stream>>>((const float*)bufA, batch, Wc1, bc1, Wc2, bc2, out, N);
}